// Round 8
// baseline (3244.917 us; speedup 1.0000x reference)
//
#include <hip/hip_runtime.h>
#include <cstdint>
#include <cstddef>

typedef unsigned int u32;
typedef unsigned short u16;
typedef float vf4 __attribute__((ext_vector_type(4)));

#define BB 16
#define CMEL 80
#define DRES 256
#define TXN 1024
#define TYN 4096
#define NEGV (-1e9f)

// output offsets (in floats), concatenated in reference return order
#define OFF_ZM    0ull
#define OFF_ZMASK 16777216ull
#define OFF_ATTN  16842752ull
#define OFF_LOGW  83951616ull
#define OFF_LOSS  83968000ull
#define OFF_MPROJ 83968001ull

// ws offsets (bytes)
#define WS_X2   0
#define WS_Z2   262144
#define WS_IDX  1310720
#define WS_PART 1572864

// ---------------- K1: row norms + z_mask ----------------
__global__ __launch_bounds__(1024) void k1_prep(
    const float* __restrict__ xm, const float* __restrict__ mel,
    const int* __restrict__ mlen,
    float* __restrict__ x2n, float* __restrict__ z2n, float* __restrict__ out_zmask) {
  int b = blockIdx.x;
  int slice = blockIdx.y;
  int t = threadIdx.x;
  if (slice == 0) {
    float acc = 0.f;
    const float* p = xm + (size_t)b * CMEL * TXN + t;
    #pragma unroll 4
    for (int c = 0; c < CMEL; ++c) { float v = p[(size_t)c * TXN]; acc = fmaf(v, v, acc); }
    x2n[b * TXN + t] = -acc;
  } else {
    int j = (slice - 1) * 1024 + t;
    float acc = 0.f;
    const float* p = mel + (size_t)b * CMEL * TYN + j;
    #pragma unroll 4
    for (int c = 0; c < CMEL; ++c) { float v = p[(size_t)c * TYN]; acc = fmaf(v, v, acc); }
    z2n[b * TYN + j] = -acc;
    out_zmask[b * TYN + j] = (j < mlen[b]) ? 1.0f : 0.0f;
  }
}

// ---------------- K2: corr GEMM -> val_T[b][j][x] (masked) ----------------
// NOTE: accumulation structure frozen — bit-matches numpy reference (absmax 0.0).
__global__ __launch_bounds__(256) void k2_corr(
    const float* __restrict__ xm, const float* __restrict__ mel,
    const float* __restrict__ x2n, const float* __restrict__ z2n,
    const int* __restrict__ xlen, const int* __restrict__ mlen,
    float* __restrict__ valT) {
  int b = blockIdx.z;
  int ml = mlen[b];
  int j0 = blockIdx.y * 128;
  if (j0 >= ml) return;   // rows never read by DP
  int xl = xlen[b];
  int x0 = blockIdx.x * 128;

  __shared__ float sA[40][128];
  __shared__ float sB[40][128];

  int t = threadIdx.x;
  int i16 = t & 15, j16 = t >> 4;

  float acc[2][4][2][4];  // [p][jj][q][i]
  #pragma unroll
  for (int p = 0; p < 2; ++p)
    #pragma unroll
    for (int jj = 0; jj < 4; ++jj)
      #pragma unroll
      for (int q = 0; q < 2; ++q)
        #pragma unroll
        for (int i = 0; i < 4; ++i) acc[p][jj][q][i] = 0.f;

  for (int c0 = 0; c0 < CMEL; c0 += 40) {
    __syncthreads();
    for (int i = t; i < 40 * 32; i += 256) {
      int c = i >> 5, q = i & 31;
      *(float4*)&sA[c][q * 4] =
          *(const float4*)(xm + (size_t)(b * CMEL + c0 + c) * TXN + x0 + q * 4);
      *(float4*)&sB[c][q * 4] =
          *(const float4*)(mel + (size_t)(b * CMEL + c0 + c) * TYN + j0 + q * 4);
    }
    __syncthreads();
    #pragma unroll 2
    for (int c = 0; c < 40; ++c) {
      float av[2][4], bw[2][4];
      *(float4*)av[0] = *(const float4*)&sA[c][i16 * 4];
      *(float4*)av[1] = *(const float4*)&sA[c][64 + i16 * 4];
      *(float4*)bw[0] = *(const float4*)&sB[c][j16 * 4];
      *(float4*)bw[1] = *(const float4*)&sB[c][64 + j16 * 4];
      #pragma unroll
      for (int p = 0; p < 2; ++p)
        #pragma unroll
        for (int jj = 0; jj < 4; ++jj)
          #pragma unroll
          for (int q = 0; q < 2; ++q)
            #pragma unroll
            for (int i = 0; i < 4; ++i)
              acc[p][jj][q][i] = fmaf(av[q][i], bw[p][jj], acc[p][jj][q][i]);
    }
  }

  float4 xa[2];
  xa[0] = *(const float4*)(x2n + b * TXN + x0 + i16 * 4);
  xa[1] = *(const float4*)(x2n + b * TXN + x0 + 64 + i16 * 4);
  int xb0 = x0 + i16 * 4;
  int xb1 = x0 + 64 + i16 * 4;

  #pragma unroll
  for (int p = 0; p < 2; ++p)
    #pragma unroll
    for (int jj = 0; jj < 4; ++jj) {
      int j = j0 + p * 64 + j16 * 4 + jj;
      if (j >= ml) continue;
      float zz = z2n[b * TYN + j];
      float* row = valT + ((size_t)b * TYN + j) * TXN;
      float4 o;
      o.x = (xb0 + 0 < xl) ? ((xa[0].x + zz) + 2.f * acc[p][jj][0][0]) : 0.f;
      o.y = (xb0 + 1 < xl) ? ((xa[0].y + zz) + 2.f * acc[p][jj][0][1]) : 0.f;
      o.z = (xb0 + 2 < xl) ? ((xa[0].z + zz) + 2.f * acc[p][jj][0][2]) : 0.f;
      o.w = (xb0 + 3 < xl) ? ((xa[0].w + zz) + 2.f * acc[p][jj][0][3]) : 0.f;
      *(float4*)(row + xb0) = o;
      o.x = (xb1 + 0 < xl) ? ((xa[1].x + zz) + 2.f * acc[p][jj][1][0]) : 0.f;
      o.y = (xb1 + 1 < xl) ? ((xa[1].y + zz) + 2.f * acc[p][jj][1][1]) : 0.f;
      o.z = (xb1 + 2 < xl) ? ((xa[1].z + zz) + 2.f * acc[p][jj][1][2]) : 0.f;
      o.w = (xb1 + 3 < xl) ? ((xa[1].w + zz) + 2.f * acc[p][jj][1][3]) : 0.f;
      *(float4*)(row + xb1) = o;
    }
}

// ---------------- K3: Viterbi forward DP (1 wave, volatile register ring) -------
// Lane owns x = 16*lane..16*lane+15. Ring rb[8][4]; prefetch loads go through a
// VOLATILE vf4* so the compiler cannot sink the issue point (R2's failure), while
// they remain ordinary IR loads so the waitcnt pass inserts *counted* vmcnt
// before uses AND before any copies of pending destinations (soundness that the
// R5-R7 asm approach lacked). Issue order: rows 0..7 in prologue; per step j:
// consume rb[j&7], then load row j+8 into that slot. Prefetch distance ~7.5
// steps (~1400 cy) > ~900 cy HBM latency.
#define RD 8
__global__ __launch_bounds__(64) void k3_dp(
    const float* __restrict__ valT, const int* __restrict__ mlen,
    u32* __restrict__ staysW) {
  const int b = blockIdx.x;
  const int ml = mlen[b];
  const int lane = threadIdx.x;
  const float* vb = valT + ((size_t)b << 22) + (lane << 4);  // lane's 16 floats/row

  vf4 rb[RD][4];
  // prologue: issue rows 0..7 (32 loads outstanding)
  #pragma unroll
  for (int r = 0; r < RD; ++r) {
    const volatile vf4* gp = (const volatile vf4*)(vb + ((size_t)r << 10));
    rb[r][0] = gp[0];
    rb[r][1] = gp[1];
    rb[r][2] = gp[2];
    rb[r][3] = gp[3];
  }

  float v[16];
  #pragma unroll
  for (int i = 0; i < 16; ++i) v[i] = NEGV;
  if (lane == 0) v[0] = 0.f;

  int gRow = RD;  // next row to issue (clamped at TYN-1)
  u16* sw16 = (u16*)staysW + (((size_t)(b * TXN + (lane << 4))) << 8);

  const int jpad = (ml + 15) & ~15;
  for (int j0 = 0; j0 < jpad; j0 += 16) {
    u32 bh[16];
    #pragma unroll
    for (int i = 0; i < 16; ++i) bh[i] = 0;

    #pragma unroll
    for (int jj = 0; jj < 16; ++jj) {
      const int j = j0 + jj;

      // 1. compute step j from rb[jj&7] (static index under unroll)
      {
        float e = __shfl_up(v[15], 1);
        if (lane == 0) e = NEGV;

        float val[16];
        #pragma unroll
        for (int q = 0; q < 4; ++q) {
          val[4 * q + 0] = rb[jj & 7][q].x;
          val[4 * q + 1] = rb[jj & 7][q].y;
          val[4 * q + 2] = rb[jj & 7][q].z;
          val[4 * q + 3] = rb[jj & 7][q].w;
        }

        #pragma unroll
        for (int i = 15; i >= 1; --i) {
          bool s = v[i] >= v[i - 1];
          v[i] = fmaxf(v[i], v[i - 1]) + val[i];
          bh[i] |= ((u32)s) << jj;
        }
        {
          bool s = v[0] >= e;
          v[0] = fmaxf(v[0], e) + val[0];
          bh[0] |= ((u32)s) << jj;
        }

        // force one-above-diagonal cell to exact NEG ((jj+1)&15 static)
        {
          int lt = (j + 1) >> 4;
          if (lane == lt) v[(jj + 1) & 15] = NEGV;
        }
      }

      // 2. issue row gRow (= j+8 until clamp) into the slot just consumed
      {
        const volatile vf4* gp = (const volatile vf4*)(vb + ((size_t)gRow << 10));
        rb[jj & 7][0] = gp[0];
        rb[jj & 7][1] = gp[1];
        rb[jj & 7][2] = gp[2];
        rb[jj & 7][3] = gp[3];
        gRow += (gRow < TYN - 1) ? 1 : 0;
      }
    }

    const int h = j0 >> 4;
    #pragma unroll
    for (int i = 0; i < 16; ++i) sw16[(i << 8) + h] = (u16)bh[i];
  }
}

// ---------------- K4: backtrack (run-skipping on transposed bits) ----------------
__global__ __launch_bounds__(256) void k4_backtrack(
    const u32* __restrict__ staysW, const int* __restrict__ xlen, const int* __restrict__ mlen,
    int* __restrict__ idxArr, float* __restrict__ out_logw) {
  int b = blockIdx.x;
  int xl = xlen[b], ml = mlen[b];
  int t = threadIdx.x;
  __shared__ u32 win[64][128];
  __shared__ u16 lidx[TYN];
  __shared__ u16 ldur[TXN];
  __shared__ int st[3];

  for (int i = t; i < TXN; i += 256) ldur[i] = 0;
  if (t == 0) { st[0] = xl - 1; st[1] = ml - 1; st[2] = ml - 1; }
  __syncthreads();

  int wb = (xl - 1) >> 6;
  for (int i = t; i < 64 * 128; i += 256) {
    int r = i >> 7, wq = i & 127;
    win[r][wq] = staysW[((size_t)(b * TXN + (wb << 6) + r) << 7) + wq];
  }
  __syncthreads();

  while (true) {
    if (t == 0) {
      int idx = st[0], j = st[1], end = st[2];
      while (j >= 0 && (idx >> 6) == wb) {
        u32 w = win[idx & 63][j >> 5];
        int p = j & 31;
        u32 below = w << (31 - p);
        u32 inv = ~below;
        int ones = (inv != 0u) ? __builtin_clz(inv) : 32;
        if (ones > p) {
          j -= p + 1;                      // whole rest of word is "stay"
        } else {
          int jz = j - ones;               // dir==0 at step jz -> move down
          for (int q = jz; q <= end; ++q) lidx[q] = (u16)idx;
          ldur[idx] = (u16)(end - jz + 1);
          end = jz - 1;
          j = jz - 1;
          idx -= 1;
        }
      }
      if (j < 0) {
        for (int q = 0; q <= end; ++q) lidx[q] = (u16)idx;
        if (idx >= 0 && end >= 0) ldur[idx] = (u16)(end + 1);
      }
      st[0] = idx; st[1] = j; st[2] = end;
    }
    __syncthreads();
    if (st[1] < 0) break;
    wb = st[0] >> 6;
    for (int i = t; i < 64 * 128; i += 256) {
      int r = i >> 7, wq = i & 127;
      win[r][wq] = staysW[((size_t)(b * TXN + (wb << 6) + r) << 7) + wq];
    }
    __syncthreads();
  }

  for (int q = t; q < TYN; q += 256) idxArr[b * TYN + q] = (q < ml) ? (int)lidx[q] : -1;
  for (int x = t; x < TXN; x += 256)
    out_logw[b * TXN + x] = (x < xl) ? logf(1e-8f + (float)ldur[x]) : 0.f;
}

// ---------------- K5a: write attn (full pass, 0/1) ----------------
__global__ __launch_bounds__(256) void k5_attn(
    const int* __restrict__ idxArr, float* __restrict__ attn) {
  int b = blockIdx.z;
  int x = blockIdx.y;
  int j = blockIdx.x * 1024 + threadIdx.x * 4;
  int4 iv = *(const int4*)(idxArr + b * TYN + j);
  float4 o;
  o.x = (iv.x == x) ? 1.f : 0.f;
  o.y = (iv.y == x) ? 1.f : 0.f;
  o.z = (iv.z == x) ? 1.f : 0.f;
  o.w = (iv.w == x) ? 1.f : 0.f;
  *(float4*)(attn + ((size_t)(b * TXN + x)) * TYN + j) = o;
}

// ---------------- K5b: z_m gather ----------------
__global__ __launch_bounds__(256) void k5_zm(
    const int* __restrict__ idxArr, const float* __restrict__ xres, float* __restrict__ zm) {
  int bid = blockIdx.x; int b = bid >> 8; int c = bid & 255;
  const float* row = xres + (size_t)(b * DRES + c) * TXN;
  float* orow = zm + (size_t)(b * DRES + c) * TYN;
  const int* ia = idxArr + b * TYN;
  for (int j = threadIdx.x; j < TYN; j += 256) {
    int idx = ia[j];
    orow[j] = (idx >= 0) ? row[idx] : 0.f;
  }
}

// ---------------- K5c: mel_proj gather + loss partials ----------------
__global__ __launch_bounds__(256) void k5_mproj(
    const int* __restrict__ idxArr, const float* __restrict__ xm,
    const float* __restrict__ noise, const float* __restrict__ mel,
    float* __restrict__ mproj, float* __restrict__ partials) {
  int bid = blockIdx.x; int b = bid / CMEL; int c = bid % CMEL;
  const float* row  = xm    + (size_t)(b * CMEL + c) * TXN;
  const float* nrow = noise + (size_t)(b * CMEL + c) * TYN;
  const float* mrow = mel   + (size_t)(b * CMEL + c) * TYN;
  float* orow = mproj + (size_t)(b * CMEL + c) * TYN;
  const int* ia = idxArr + b * TYN;
  float acc = 0.f;
  for (int j = threadIdx.x; j < TYN; j += 256) {
    int idx = ia[j];
    float g = (idx >= 0) ? row[idx] : 0.f;
    float mp = g + nrow[j];
    orow[j] = mp;
    float d = mp - mrow[j];
    acc += (idx >= 0) ? fabsf(d) : 0.f;
  }
  #pragma unroll
  for (int o = 32; o; o >>= 1) acc += __shfl_down(acc, o);
  __shared__ float ws4[4];
  if ((threadIdx.x & 63) == 0) ws4[threadIdx.x >> 6] = acc;
  __syncthreads();
  if (threadIdx.x == 0) partials[bid] = (ws4[0] + ws4[1]) + (ws4[2] + ws4[3]);
}

// ---------------- K6: final loss reduce ----------------
__global__ __launch_bounds__(256) void k6_loss(
    const float* __restrict__ partials, float* __restrict__ out_loss) {
  float acc = 0.f;
  for (int i = threadIdx.x; i < BB * CMEL; i += 256) acc += partials[i];
  #pragma unroll
  for (int o = 32; o; o >>= 1) acc += __shfl_down(acc, o);
  __shared__ float ws4[4];
  if ((threadIdx.x & 63) == 0) ws4[threadIdx.x >> 6] = acc;
  __syncthreads();
  if (threadIdx.x == 0)
    out_loss[0] = ((ws4[0] + ws4[1]) + (ws4[2] + ws4[3])) * (1.0f / ((float)BB * CMEL * TYN));
}

extern "C" void kernel_launch(void* const* d_in, const int* in_sizes, int n_in,
                              void* d_out, int out_size, void* d_ws, size_t ws_size,
                              hipStream_t stream) {
  const float* xm    = (const float*)d_in[0];
  const float* xres  = (const float*)d_in[1];
  const float* mel   = (const float*)d_in[2];
  const int*   xlen  = (const int*)d_in[3];
  const int*   mlen  = (const int*)d_in[4];
  const float* noise = (const float*)d_in[5];

  float* out = (float*)d_out;
  float* out_zm    = out + OFF_ZM;
  float* out_zmask = out + OFF_ZMASK;
  float* out_attn  = out + OFF_ATTN;
  float* out_logw  = out + OFF_LOGW;
  float* out_loss  = out + OFF_LOSS;
  float* out_mproj = out + OFF_MPROJ;

  char* ws = (char*)d_ws;
  float* x2n      = (float*)(ws + WS_X2);
  float* z2n      = (float*)(ws + WS_Z2);
  int*   idxArr   = (int*)(ws + WS_IDX);
  float* partials = (float*)(ws + WS_PART);

  // scratch aliases inside output regions (consumed before region is rewritten)
  float* valT   = out_attn;        // [b][j][x], read by K3, overwritten by K5a
  u32*   staysW = (u32*)out_zm;    // 8 MB of z_m region, read by K4, overwritten by K5b

  hipLaunchKernelGGL(k1_prep, dim3(BB, 5), dim3(1024), 0, stream, xm, mel, mlen, x2n, z2n, out_zmask);
  hipLaunchKernelGGL(k2_corr, dim3(8, 32, BB), dim3(256), 0, stream, xm, mel, x2n, z2n, xlen, mlen, valT);
  hipLaunchKernelGGL(k3_dp, dim3(BB), dim3(64), 0, stream, valT, mlen, staysW);
  hipLaunchKernelGGL(k4_backtrack, dim3(BB), dim3(256), 0, stream, staysW, xlen, mlen, idxArr, out_logw);
  hipLaunchKernelGGL(k5_attn, dim3(4, TXN, BB), dim3(256), 0, stream, idxArr, out_attn);
  hipLaunchKernelGGL(k5_zm, dim3(BB * DRES), dim3(256), 0, stream, idxArr, xres, out_zm);
  hipLaunchKernelGGL(k5_mproj, dim3(BB * CMEL), dim3(256), 0, stream, idxArr, xm, noise, mel, out_mproj, partials);
  hipLaunchKernelGGL(k6_loss, dim3(1), dim3(256), 0, stream, partials, out_loss);
}

// Round 9
// 2638.623 us; speedup vs baseline: 1.2298x; 1.2298x over previous
//
#include <hip/hip_runtime.h>
#include <cstdint>
#include <cstddef>

typedef unsigned int u32;
typedef unsigned short u16;
typedef float vf4 __attribute__((ext_vector_type(4)));

#define BB 16
#define CMEL 80
#define DRES 256
#define TXN 1024
#define TYN 4096
#define NEGV (-1e9f)

// output offsets (in floats), concatenated in reference return order
#define OFF_ZM    0ull
#define OFF_ZMASK 16777216ull
#define OFF_ATTN  16842752ull
#define OFF_LOGW  83951616ull
#define OFF_LOSS  83968000ull
#define OFF_MPROJ 83968001ull

// ws offsets (bytes)
#define WS_X2   0
#define WS_Z2   262144
#define WS_IDX  1310720
#define WS_PART 1572864

// ---------------- K1: row norms + z_mask ----------------
__global__ __launch_bounds__(1024) void k1_prep(
    const float* __restrict__ xm, const float* __restrict__ mel,
    const int* __restrict__ mlen,
    float* __restrict__ x2n, float* __restrict__ z2n, float* __restrict__ out_zmask) {
  int b = blockIdx.x;
  int slice = blockIdx.y;
  int t = threadIdx.x;
  if (slice == 0) {
    float acc = 0.f;
    const float* p = xm + (size_t)b * CMEL * TXN + t;
    #pragma unroll 4
    for (int c = 0; c < CMEL; ++c) { float v = p[(size_t)c * TXN]; acc = fmaf(v, v, acc); }
    x2n[b * TXN + t] = -acc;
  } else {
    int j = (slice - 1) * 1024 + t;
    float acc = 0.f;
    const float* p = mel + (size_t)b * CMEL * TYN + j;
    #pragma unroll 4
    for (int c = 0; c < CMEL; ++c) { float v = p[(size_t)c * TYN]; acc = fmaf(v, v, acc); }
    z2n[b * TYN + j] = -acc;
    out_zmask[b * TYN + j] = (j < mlen[b]) ? 1.0f : 0.0f;
  }
}

// ---------------- K2: corr GEMM -> val_T[b][j][x] (masked) ----------------
// NOTE: accumulation structure frozen — bit-matches numpy reference (absmax 0.0).
__global__ __launch_bounds__(256) void k2_corr(
    const float* __restrict__ xm, const float* __restrict__ mel,
    const float* __restrict__ x2n, const float* __restrict__ z2n,
    const int* __restrict__ xlen, const int* __restrict__ mlen,
    float* __restrict__ valT) {
  int b = blockIdx.z;
  int ml = mlen[b];
  int j0 = blockIdx.y * 128;
  if (j0 >= ml) return;   // rows never read by DP
  int xl = xlen[b];
  int x0 = blockIdx.x * 128;

  __shared__ float sA[40][128];
  __shared__ float sB[40][128];

  int t = threadIdx.x;
  int i16 = t & 15, j16 = t >> 4;

  float acc[2][4][2][4];  // [p][jj][q][i]
  #pragma unroll
  for (int p = 0; p < 2; ++p)
    #pragma unroll
    for (int jj = 0; jj < 4; ++jj)
      #pragma unroll
      for (int q = 0; q < 2; ++q)
        #pragma unroll
        for (int i = 0; i < 4; ++i) acc[p][jj][q][i] = 0.f;

  for (int c0 = 0; c0 < CMEL; c0 += 40) {
    __syncthreads();
    for (int i = t; i < 40 * 32; i += 256) {
      int c = i >> 5, q = i & 31;
      *(float4*)&sA[c][q * 4] =
          *(const float4*)(xm + (size_t)(b * CMEL + c0 + c) * TXN + x0 + q * 4);
      *(float4*)&sB[c][q * 4] =
          *(const float4*)(mel + (size_t)(b * CMEL + c0 + c) * TYN + j0 + q * 4);
    }
    __syncthreads();
    #pragma unroll 2
    for (int c = 0; c < 40; ++c) {
      float av[2][4], bw[2][4];
      *(float4*)av[0] = *(const float4*)&sA[c][i16 * 4];
      *(float4*)av[1] = *(const float4*)&sA[c][64 + i16 * 4];
      *(float4*)bw[0] = *(const float4*)&sB[c][j16 * 4];
      *(float4*)bw[1] = *(const float4*)&sB[c][64 + j16 * 4];
      #pragma unroll
      for (int p = 0; p < 2; ++p)
        #pragma unroll
        for (int jj = 0; jj < 4; ++jj)
          #pragma unroll
          for (int q = 0; q < 2; ++q)
            #pragma unroll
            for (int i = 0; i < 4; ++i)
              acc[p][jj][q][i] = fmaf(av[q][i], bw[p][jj], acc[p][jj][q][i]);
    }
  }

  float4 xa[2];
  xa[0] = *(const float4*)(x2n + b * TXN + x0 + i16 * 4);
  xa[1] = *(const float4*)(x2n + b * TXN + x0 + 64 + i16 * 4);
  int xb0 = x0 + i16 * 4;
  int xb1 = x0 + 64 + i16 * 4;

  #pragma unroll
  for (int p = 0; p < 2; ++p)
    #pragma unroll
    for (int jj = 0; jj < 4; ++jj) {
      int j = j0 + p * 64 + j16 * 4 + jj;
      if (j >= ml) continue;
      float zz = z2n[b * TYN + j];
      float* row = valT + ((size_t)b * TYN + j) * TXN;
      float4 o;
      o.x = (xb0 + 0 < xl) ? ((xa[0].x + zz) + 2.f * acc[p][jj][0][0]) : 0.f;
      o.y = (xb0 + 1 < xl) ? ((xa[0].y + zz) + 2.f * acc[p][jj][0][1]) : 0.f;
      o.z = (xb0 + 2 < xl) ? ((xa[0].z + zz) + 2.f * acc[p][jj][0][2]) : 0.f;
      o.w = (xb0 + 3 < xl) ? ((xa[0].w + zz) + 2.f * acc[p][jj][0][3]) : 0.f;
      *(float4*)(row + xb0) = o;
      o.x = (xb1 + 0 < xl) ? ((xa[1].x + zz) + 2.f * acc[p][jj][1][0]) : 0.f;
      o.y = (xb1 + 1 < xl) ? ((xa[1].y + zz) + 2.f * acc[p][jj][1][1]) : 0.f;
      o.z = (xb1 + 2 < xl) ? ((xa[1].z + zz) + 2.f * acc[p][jj][1][2]) : 0.f;
      o.w = (xb1 + 3 < xl) ? ((xa[1].w + zz) + 2.f * acc[p][jj][1][3]) : 0.f;
      *(float4*)(row + xb1) = o;
    }
}

// ---------------- K3: Viterbi DP — in-WG producer/consumer LDS ring ------------
// 8 waves: wid 0..6 producers (row r handled by wave r%7), wid 7 = DP consumer.
// Ring: 16 slots x 4KB LDS, quarter-major layout (LDS float 256q+4*lane holds
// global row float 16*lane+4q.. — R4's proven-correct layout; conflict-free
// ds_write/ds_read_b128 on both sides). Sync: pprog[p] (producer p completed
// rows < pprog[p]; BIG sentinel on exit) + rdone (consumer computed rows < rdone,
// published every 4 steps; slot of row r reusable when rdone >= r-15).
// Ordering: producer ds_writes -> __threadfence_block() -> pprog store;
// consumer flag-spin -> asm memory fence -> data ds_reads. No per-step barriers.
// Consumer prefetch distance 2 (row j+2 read at step j). Deadlock-free: a
// producer blocked on slot r needs rdone>=r-15, and the consumer blocking on a
// lagging producer at row t<=j+2 implies rdone=j+1>=t-15 — producer not blocked.
#define NSLOT 16
__global__ __launch_bounds__(512) void k3_dp(
    const float* __restrict__ valT, const int* __restrict__ mlen,
    u32* __restrict__ staysW) {
  __shared__ float ring[NSLOT * 1024];  // 64 KB
  __shared__ u32 pprog[8];
  __shared__ u32 rdoneS;

  const int b = blockIdx.x;
  const int ml = mlen[b];
  const int jpad = (ml + 15) & ~15;
  const int t = threadIdx.x;
  const int wid = t >> 6, lane = t & 63;
  const float* base = valT + ((size_t)b << 22);

  if (t == 0) {
    rdoneS = 0;
    #pragma unroll
    for (int i = 0; i < 8; ++i) pprog[i] = 0;
  }
  __syncthreads();

  if (wid < 7) {
    // ---------------- producer ----------------
    volatile u32* ppv = &pprog[wid];
    const u32* rdp = (const u32*)&rdoneS;
    u32 rl = 0;
    for (int r = wid; r < jpad; r += 7) {
      // global source pre-swizzled for quarter-major LDS: chunk g = floats
      // row*1024 + 16*lane + 4g (same addressing as R4's correct kernel)
      const float* gp = base + ((size_t)r << 10) + (lane << 4);
      vf4 a0 = *(const vf4*)(gp);
      vf4 a1 = *(const vf4*)(gp + 4);
      vf4 a2 = *(const vf4*)(gp + 8);
      vf4 a3 = *(const vf4*)(gp + 12);
      // slot free when consumer computed row r-16: rdone >= r-15
      while (rl + (NSLOT - 1) < (u32)r) {
        asm volatile("" ::: "memory");
        rl = *rdp;
      }
      asm volatile("" ::: "memory");
      float* lp = &ring[((r & (NSLOT - 1)) << 10) + (lane << 2)];
      *(vf4*)(lp)       = a0;   // quarter 0 @ float 4*lane
      *(vf4*)(lp + 256) = a1;   // quarter 1
      *(vf4*)(lp + 512) = a2;   // quarter 2
      *(vf4*)(lp + 768) = a3;   // quarter 3
      __threadfence_block();    // ds_writes complete + ordered before flag
      *ppv = (u32)(r + 1);
    }
    *ppv = 0x7fffffffu;         // sentinel: this producer done (tail liveness)
    return;
  }

  // ---------------- consumer (wid == 7) ----------------
  const u32* pp = (const u32*)pprog;
  volatile u32* rdv = &rdoneS;
  u32 jr = 0;

#define REFRESH_JR() do { \
    asm volatile("" ::: "memory"); \
    u32 m0 = pp[0], m1 = pp[1], m2 = pp[2], m3 = pp[3]; \
    u32 m4 = pp[4], m5 = pp[5], m6 = pp[6]; \
    m0 = m0 < m1 ? m0 : m1; m2 = m2 < m3 ? m2 : m3; m4 = m4 < m5 ? m4 : m5; \
    m0 = m0 < m2 ? m0 : m2; m4 = m4 < m6 ? m4 : m6; \
    jr = (m0 < m4 ? m0 : m4); \
  } while (0)

  while (jr < 2u) REFRESH_JR();
  asm volatile("" ::: "memory");

  vf4 dbuf[4][4];
  #pragma unroll
  for (int q = 0; q < 4; ++q) {
    dbuf[0][q] = *(const vf4*)&ring[(0 << 10) + (q << 8) + (lane << 2)];
    dbuf[1][q] = *(const vf4*)&ring[(1 << 10) + (q << 8) + (lane << 2)];
  }

  float v[16];
  #pragma unroll
  for (int i = 0; i < 16; ++i) v[i] = NEGV;
  if (lane == 0) v[0] = 0.f;

  u16* sw16 = (u16*)staysW + (((size_t)(b * TXN + (lane << 4))) << 8);

  for (int j0 = 0; j0 < jpad; j0 += 16) {
    u32 bh[16];
    #pragma unroll
    for (int i = 0; i < 16; ++i) bh[i] = 0;

    #pragma unroll
    for (int jj = 0; jj < 16; ++jj) {
      const int j = j0 + jj;

      // 1. ensure row j+2 published, then prefetch it into dbuf[(jj+2)&3]
      while (jr < (u32)(j + 3)) REFRESH_JR();
      asm volatile("" ::: "memory");
      {
        int pr = j + 2; if (pr > jpad - 1) pr = jpad - 1;
        const int s = (pr & (NSLOT - 1)) << 10;
        #pragma unroll
        for (int q = 0; q < 4; ++q)
          dbuf[(jj + 2) & 3][q] = *(const vf4*)&ring[s + (q << 8) + (lane << 2)];
      }

      // 2. compute step j from dbuf[jj&3] (static index under unroll)
      {
        float e = __shfl_up(v[15], 1);
        if (lane == 0) e = NEGV;

        float val[16];
        #pragma unroll
        for (int q = 0; q < 4; ++q) {
          val[4 * q + 0] = dbuf[jj & 3][q].x;
          val[4 * q + 1] = dbuf[jj & 3][q].y;
          val[4 * q + 2] = dbuf[jj & 3][q].z;
          val[4 * q + 3] = dbuf[jj & 3][q].w;
        }

        #pragma unroll
        for (int i = 15; i >= 1; --i) {
          bool s = v[i] >= v[i - 1];
          v[i] = fmaxf(v[i], v[i - 1]) + val[i];
          bh[i] |= ((u32)s) << jj;
        }
        {
          bool s = v[0] >= e;
          v[0] = fmaxf(v[0], e) + val[0];
          bh[0] |= ((u32)s) << jj;
        }

        // force one-above-diagonal cell to exact NEG ((jj+1)&15 static)
        {
          int lt = (j + 1) >> 4;
          if (lane == lt) v[(jj + 1) & 15] = NEGV;
        }
      }

      // 3. publish consumption progress every 4 steps (slot-free signal)
      if (((jj & 3) == 3) && lane == 0) *rdv = (u32)(j + 1);
    }

    const int h = j0 >> 4;
    #pragma unroll
    for (int i = 0; i < 16; ++i) sw16[(i << 8) + h] = (u16)bh[i];
  }
#undef REFRESH_JR
}

// ---------------- K4: backtrack (run-skipping on transposed bits) ----------------
__global__ __launch_bounds__(256) void k4_backtrack(
    const u32* __restrict__ staysW, const int* __restrict__ xlen, const int* __restrict__ mlen,
    int* __restrict__ idxArr, float* __restrict__ out_logw) {
  int b = blockIdx.x;
  int xl = xlen[b], ml = mlen[b];
  int t = threadIdx.x;
  __shared__ u32 win[64][128];
  __shared__ u16 lidx[TYN];
  __shared__ u16 ldur[TXN];
  __shared__ int st[3];

  for (int i = t; i < TXN; i += 256) ldur[i] = 0;
  if (t == 0) { st[0] = xl - 1; st[1] = ml - 1; st[2] = ml - 1; }
  __syncthreads();

  int wb = (xl - 1) >> 6;
  for (int i = t; i < 64 * 128; i += 256) {
    int r = i >> 7, wq = i & 127;
    win[r][wq] = staysW[((size_t)(b * TXN + (wb << 6) + r) << 7) + wq];
  }
  __syncthreads();

  while (true) {
    if (t == 0) {
      int idx = st[0], j = st[1], end = st[2];
      while (j >= 0 && (idx >> 6) == wb) {
        u32 w = win[idx & 63][j >> 5];
        int p = j & 31;
        u32 below = w << (31 - p);
        u32 inv = ~below;
        int ones = (inv != 0u) ? __builtin_clz(inv) : 32;
        if (ones > p) {
          j -= p + 1;                      // whole rest of word is "stay"
        } else {
          int jz = j - ones;               // dir==0 at step jz -> move down
          for (int q = jz; q <= end; ++q) lidx[q] = (u16)idx;
          ldur[idx] = (u16)(end - jz + 1);
          end = jz - 1;
          j = jz - 1;
          idx -= 1;
        }
      }
      if (j < 0) {
        for (int q = 0; q <= end; ++q) lidx[q] = (u16)idx;
        if (idx >= 0 && end >= 0) ldur[idx] = (u16)(end + 1);
      }
      st[0] = idx; st[1] = j; st[2] = end;
    }
    __syncthreads();
    if (st[1] < 0) break;
    wb = st[0] >> 6;
    for (int i = t; i < 64 * 128; i += 256) {
      int r = i >> 7, wq = i & 127;
      win[r][wq] = staysW[((size_t)(b * TXN + (wb << 6) + r) << 7) + wq];
    }
    __syncthreads();
  }

  for (int q = t; q < TYN; q += 256) idxArr[b * TYN + q] = (q < ml) ? (int)lidx[q] : -1;
  for (int x = t; x < TXN; x += 256)
    out_logw[b * TXN + x] = (x < xl) ? logf(1e-8f + (float)ldur[x]) : 0.f;
}

// ---------------- K5a: write attn (full pass, 0/1) ----------------
__global__ __launch_bounds__(256) void k5_attn(
    const int* __restrict__ idxArr, float* __restrict__ attn) {
  int b = blockIdx.z;
  int x = blockIdx.y;
  int j = blockIdx.x * 1024 + threadIdx.x * 4;
  int4 iv = *(const int4*)(idxArr + b * TYN + j);
  float4 o;
  o.x = (iv.x == x) ? 1.f : 0.f;
  o.y = (iv.y == x) ? 1.f : 0.f;
  o.z = (iv.z == x) ? 1.f : 0.f;
  o.w = (iv.w == x) ? 1.f : 0.f;
  *(float4*)(attn + ((size_t)(b * TXN + x)) * TYN + j) = o;
}

// ---------------- K5b: z_m gather ----------------
__global__ __launch_bounds__(256) void k5_zm(
    const int* __restrict__ idxArr, const float* __restrict__ xres, float* __restrict__ zm) {
  int bid = blockIdx.x; int b = bid >> 8; int c = bid & 255;
  const float* row = xres + (size_t)(b * DRES + c) * TXN;
  float* orow = zm + (size_t)(b * DRES + c) * TYN;
  const int* ia = idxArr + b * TYN;
  for (int j = threadIdx.x; j < TYN; j += 256) {
    int idx = ia[j];
    orow[j] = (idx >= 0) ? row[idx] : 0.f;
  }
}

// ---------------- K5c: mel_proj gather + loss partials ----------------
__global__ __launch_bounds__(256) void k5_mproj(
    const int* __restrict__ idxArr, const float* __restrict__ xm,
    const float* __restrict__ noise, const float* __restrict__ mel,
    float* __restrict__ mproj, float* __restrict__ partials) {
  int bid = blockIdx.x; int b = bid / CMEL; int c = bid % CMEL;
  const float* row  = xm    + (size_t)(b * CMEL + c) * TXN;
  const float* nrow = noise + (size_t)(b * CMEL + c) * TYN;
  const float* mrow = mel   + (size_t)(b * CMEL + c) * TYN;
  float* orow = mproj + (size_t)(b * CMEL + c) * TYN;
  const int* ia = idxArr + b * TYN;
  float acc = 0.f;
  for (int j = threadIdx.x; j < TYN; j += 256) {
    int idx = ia[j];
    float g = (idx >= 0) ? row[idx] : 0.f;
    float mp = g + nrow[j];
    orow[j] = mp;
    float d = mp - mrow[j];
    acc += (idx >= 0) ? fabsf(d) : 0.f;
  }
  #pragma unroll
  for (int o = 32; o; o >>= 1) acc += __shfl_down(acc, o);
  __shared__ float ws4[4];
  if ((threadIdx.x & 63) == 0) ws4[threadIdx.x >> 6] = acc;
  __syncthreads();
  if (threadIdx.x == 0) partials[bid] = (ws4[0] + ws4[1]) + (ws4[2] + ws4[3]);
}

// ---------------- K6: final loss reduce ----------------
__global__ __launch_bounds__(256) void k6_loss(
    const float* __restrict__ partials, float* __restrict__ out_loss) {
  float acc = 0.f;
  for (int i = threadIdx.x; i < BB * CMEL; i += 256) acc += partials[i];
  #pragma unroll
  for (int o = 32; o; o >>= 1) acc += __shfl_down(acc, o);
  __shared__ float ws4[4];
  if ((threadIdx.x & 63) == 0) ws4[threadIdx.x >> 6] = acc;
  __syncthreads();
  if (threadIdx.x == 0)
    out_loss[0] = ((ws4[0] + ws4[1]) + (ws4[2] + ws4[3])) * (1.0f / ((float)BB * CMEL * TYN));
}

extern "C" void kernel_launch(void* const* d_in, const int* in_sizes, int n_in,
                              void* d_out, int out_size, void* d_ws, size_t ws_size,
                              hipStream_t stream) {
  const float* xm    = (const float*)d_in[0];
  const float* xres  = (const float*)d_in[1];
  const float* mel   = (const float*)d_in[2];
  const int*   xlen  = (const int*)d_in[3];
  const int*   mlen  = (const int*)d_in[4];
  const float* noise = (const float*)d_in[5];

  float* out = (float*)d_out;
  float* out_zm    = out + OFF_ZM;
  float* out_zmask = out + OFF_ZMASK;
  float* out_attn  = out + OFF_ATTN;
  float* out_logw  = out + OFF_LOGW;
  float* out_loss  = out + OFF_LOSS;
  float* out_mproj = out + OFF_MPROJ;

  char* ws = (char*)d_ws;
  float* x2n      = (float*)(ws + WS_X2);
  float* z2n      = (float*)(ws + WS_Z2);
  int*   idxArr   = (int*)(ws + WS_IDX);
  float* partials = (float*)(ws + WS_PART);

  // scratch aliases inside output regions (consumed before region is rewritten)
  float* valT   = out_attn;        // [b][j][x], read by K3, overwritten by K5a
  u32*   staysW = (u32*)out_zm;    // 8 MB of z_m region, read by K4, overwritten by K5b

  hipLaunchKernelGGL(k1_prep, dim3(BB, 5), dim3(1024), 0, stream, xm, mel, mlen, x2n, z2n, out_zmask);
  hipLaunchKernelGGL(k2_corr, dim3(8, 32, BB), dim3(256), 0, stream, xm, mel, x2n, z2n, xlen, mlen, valT);
  hipLaunchKernelGGL(k3_dp, dim3(BB), dim3(512), 0, stream, valT, mlen, staysW);
  hipLaunchKernelGGL(k4_backtrack, dim3(BB), dim3(256), 0, stream, staysW, xlen, mlen, idxArr, out_logw);
  hipLaunchKernelGGL(k5_attn, dim3(4, TXN, BB), dim3(256), 0, stream, idxArr, out_attn);
  hipLaunchKernelGGL(k5_zm, dim3(BB * DRES), dim3(256), 0, stream, idxArr, xres, out_zm);
  hipLaunchKernelGGL(k5_mproj, dim3(BB * CMEL), dim3(256), 0, stream, idxArr, xm, noise, mel, out_mproj, partials);
  hipLaunchKernelGGL(k6_loss, dim3(1), dim3(256), 0, stream, partials, out_loss);
}

// Round 10
// 1305.960 us; speedup vs baseline: 2.4847x; 2.0204x over previous
//
#include <hip/hip_runtime.h>
#include <cstdint>
#include <cstddef>

typedef unsigned int u32;
typedef unsigned short u16;
typedef float vf4 __attribute__((ext_vector_type(4)));

#define BB 16
#define CMEL 80
#define DRES 256
#define TXN 1024
#define TYN 4096
#define NEGV (-1e9f)

// output offsets (in floats), concatenated in reference return order
#define OFF_ZM    0ull
#define OFF_ZMASK 16777216ull
#define OFF_ATTN  16842752ull
#define OFF_LOGW  83951616ull
#define OFF_LOSS  83968000ull
#define OFF_MPROJ 83968001ull

// ws offsets (bytes)
#define WS_X2   0
#define WS_Z2   262144
#define WS_IDX  1310720
#define WS_PART 1572864

// ---------------- K1: row norms + z_mask ----------------
__global__ __launch_bounds__(1024) void k1_prep(
    const float* __restrict__ xm, const float* __restrict__ mel,
    const int* __restrict__ mlen,
    float* __restrict__ x2n, float* __restrict__ z2n, float* __restrict__ out_zmask) {
  int b = blockIdx.x;
  int slice = blockIdx.y;
  int t = threadIdx.x;
  if (slice == 0) {
    float acc = 0.f;
    const float* p = xm + (size_t)b * CMEL * TXN + t;
    #pragma unroll 4
    for (int c = 0; c < CMEL; ++c) { float v = p[(size_t)c * TXN]; acc = fmaf(v, v, acc); }
    x2n[b * TXN + t] = -acc;
  } else {
    int j = (slice - 1) * 1024 + t;
    float acc = 0.f;
    const float* p = mel + (size_t)b * CMEL * TYN + j;
    #pragma unroll 4
    for (int c = 0; c < CMEL; ++c) { float v = p[(size_t)c * TYN]; acc = fmaf(v, v, acc); }
    z2n[b * TYN + j] = -acc;
    out_zmask[b * TYN + j] = (j < mlen[b]) ? 1.0f : 0.0f;
  }
}

// ---------------- K2: corr GEMM -> val_T[b][j][x] (masked) ----------------
// NOTE: accumulation structure frozen — bit-matches numpy reference (absmax 0.0).
__global__ __launch_bounds__(256) void k2_corr(
    const float* __restrict__ xm, const float* __restrict__ mel,
    const float* __restrict__ x2n, const float* __restrict__ z2n,
    const int* __restrict__ xlen, const int* __restrict__ mlen,
    float* __restrict__ valT) {
  int b = blockIdx.z;
  int ml = mlen[b];
  int j0 = blockIdx.y * 128;
  if (j0 >= ml) return;   // rows never read by DP
  int xl = xlen[b];
  int x0 = blockIdx.x * 128;

  __shared__ float sA[40][128];
  __shared__ float sB[40][128];

  int t = threadIdx.x;
  int i16 = t & 15, j16 = t >> 4;

  float acc[2][4][2][4];  // [p][jj][q][i]
  #pragma unroll
  for (int p = 0; p < 2; ++p)
    #pragma unroll
    for (int jj = 0; jj < 4; ++jj)
      #pragma unroll
      for (int q = 0; q < 2; ++q)
        #pragma unroll
        for (int i = 0; i < 4; ++i) acc[p][jj][q][i] = 0.f;

  for (int c0 = 0; c0 < CMEL; c0 += 40) {
    __syncthreads();
    for (int i = t; i < 40 * 32; i += 256) {
      int c = i >> 5, q = i & 31;
      *(float4*)&sA[c][q * 4] =
          *(const float4*)(xm + (size_t)(b * CMEL + c0 + c) * TXN + x0 + q * 4);
      *(float4*)&sB[c][q * 4] =
          *(const float4*)(mel + (size_t)(b * CMEL + c0 + c) * TYN + j0 + q * 4);
    }
    __syncthreads();
    #pragma unroll 2
    for (int c = 0; c < 40; ++c) {
      float av[2][4], bw[2][4];
      *(float4*)av[0] = *(const float4*)&sA[c][i16 * 4];
      *(float4*)av[1] = *(const float4*)&sA[c][64 + i16 * 4];
      *(float4*)bw[0] = *(const float4*)&sB[c][j16 * 4];
      *(float4*)bw[1] = *(const float4*)&sB[c][64 + j16 * 4];
      #pragma unroll
      for (int p = 0; p < 2; ++p)
        #pragma unroll
        for (int jj = 0; jj < 4; ++jj)
          #pragma unroll
          for (int q = 0; q < 2; ++q)
            #pragma unroll
            for (int i = 0; i < 4; ++i)
              acc[p][jj][q][i] = fmaf(av[q][i], bw[p][jj], acc[p][jj][q][i]);
    }
  }

  float4 xa[2];
  xa[0] = *(const float4*)(x2n + b * TXN + x0 + i16 * 4);
  xa[1] = *(const float4*)(x2n + b * TXN + x0 + 64 + i16 * 4);
  int xb0 = x0 + i16 * 4;
  int xb1 = x0 + 64 + i16 * 4;

  #pragma unroll
  for (int p = 0; p < 2; ++p)
    #pragma unroll
    for (int jj = 0; jj < 4; ++jj) {
      int j = j0 + p * 64 + j16 * 4 + jj;
      if (j >= ml) continue;
      float zz = z2n[b * TYN + j];
      float* row = valT + ((size_t)b * TYN + j) * TXN;
      float4 o;
      o.x = (xb0 + 0 < xl) ? ((xa[0].x + zz) + 2.f * acc[p][jj][0][0]) : 0.f;
      o.y = (xb0 + 1 < xl) ? ((xa[0].y + zz) + 2.f * acc[p][jj][0][1]) : 0.f;
      o.z = (xb0 + 2 < xl) ? ((xa[0].z + zz) + 2.f * acc[p][jj][0][2]) : 0.f;
      o.w = (xb0 + 3 < xl) ? ((xa[0].w + zz) + 2.f * acc[p][jj][0][3]) : 0.f;
      *(float4*)(row + xb0) = o;
      o.x = (xb1 + 0 < xl) ? ((xa[1].x + zz) + 2.f * acc[p][jj][1][0]) : 0.f;
      o.y = (xb1 + 1 < xl) ? ((xa[1].y + zz) + 2.f * acc[p][jj][1][1]) : 0.f;
      o.z = (xb1 + 2 < xl) ? ((xa[1].z + zz) + 2.f * acc[p][jj][1][2]) : 0.f;
      o.w = (xb1 + 3 < xl) ? ((xa[1].w + zz) + 2.f * acc[p][jj][1][3]) : 0.f;
      *(float4*)(row + xb1) = o;
    }
}

// ---------------- K3: Viterbi DP (1 wave, double-buffered register blocks) ------
// Lane owns x = 16*lane..16*lane+15. Two 8-row register buffers bA/bB (256 VGPR;
// __launch_bounds__(64,1) allows up to 512, no spill through ~450). Per 16-step
// iteration: compute 8 steps from bA | SCHED_BARRIER | issue plain loads rows
// j0+16..23 into bA | SCHED_BARRIER | compute 8 from bB | SB | issue rows
// j0+24..31 into bB | SB | store bits. sched_barrier(0) pins the load-issue
// point (R2's failure was the scheduler sinking loads to use); plain loads keep
// the waitcnt pass in COUNTED mode (R4/R8/R9 lost to serialization from
// LDS-DMA/volatile/asm-fence memory semantics — none of those appear here).
// Issue->use distance = 8 steps (~1500 cy) > ~900 cy HBM latency.
// All v[]/buffer indices compile-time static (no scratch, rule #20).
__global__ __launch_bounds__(64, 1) void k3_dp(
    const float* __restrict__ valT, const int* __restrict__ mlen,
    u32* __restrict__ staysW) {
  const int b = blockIdx.x;
  const int ml = mlen[b];
  const int lane = threadIdx.x;
  const float* vb = valT + ((size_t)b << 22) + (lane << 4);  // lane's 16 floats/row

  vf4 bA[8][4], bB[8][4];
  // prologue: rows 0..7 -> bA, rows 8..15 -> bB
  #pragma unroll
  for (int r = 0; r < 8; ++r) {
    const float* gp = vb + ((size_t)r << 10);
    #pragma unroll
    for (int q = 0; q < 4; ++q) bA[r][q] = *(const vf4*)(gp + (q << 2));
  }
  #pragma unroll
  for (int r = 0; r < 8; ++r) {
    const float* gp = vb + ((size_t)(r + 8) << 10);
    #pragma unroll
    for (int q = 0; q < 4; ++q) bB[r][q] = *(const vf4*)(gp + (q << 2));
  }

  float v[16];
  #pragma unroll
  for (int i = 0; i < 16; ++i) v[i] = NEGV;
  if (lane == 0) v[0] = 0.f;

  u16* sw16 = (u16*)staysW + (((size_t)(b * TXN + (lane << 4))) << 8);
  const int jpad = (ml + 15) & ~15;

  // one DP step: uses buffer row `src`, bit position `bp`, NEG-force reg `fi`
#define DP_STEP(src, j, bp, fi)                                         \
  {                                                                     \
    float e = __shfl_up(v[15], 1);                                      \
    if (lane == 0) e = NEGV;                                            \
    float val[16];                                                      \
    _Pragma("unroll")                                                   \
    for (int q = 0; q < 4; ++q) {                                       \
      val[4 * q + 0] = (src)[q].x;                                      \
      val[4 * q + 1] = (src)[q].y;                                      \
      val[4 * q + 2] = (src)[q].z;                                      \
      val[4 * q + 3] = (src)[q].w;                                      \
    }                                                                   \
    _Pragma("unroll")                                                   \
    for (int i = 15; i >= 1; --i) {                                     \
      bool st = v[i] >= v[i - 1];                                       \
      v[i] = fmaxf(v[i], v[i - 1]) + val[i];                            \
      bh[i] |= ((u32)st) << (bp);                                       \
    }                                                                   \
    {                                                                   \
      bool st = v[0] >= e;                                              \
      v[0] = fmaxf(v[0], e) + val[0];                                   \
      bh[0] |= ((u32)st) << (bp);                                       \
    }                                                                   \
    {                                                                   \
      int lt = ((j) + 1) >> 4;                                          \
      if (lane == lt) v[(fi)] = NEGV;                                   \
    }                                                                   \
  }

  for (int j0 = 0; j0 < jpad; j0 += 16) {
    u32 bh[16];
    #pragma unroll
    for (int i = 0; i < 16; ++i) bh[i] = 0;

    __builtin_amdgcn_sched_barrier(0);
    // half 0: steps j0+0..j0+7 from bA (bit positions 0..7, force idx s+1)
    #pragma unroll
    for (int s = 0; s < 8; ++s) DP_STEP(bA[s], j0 + s, s, (s + 1) & 15);
    __builtin_amdgcn_sched_barrier(0);

    // issue loads rows j0+16..j0+23 into bA (used next iteration, half 0)
    #pragma unroll
    for (int r = 0; r < 8; ++r) {
      int rr = j0 + 16 + r; if (rr > TYN - 1) rr = TYN - 1;
      const float* gp = vb + ((size_t)rr << 10);
      #pragma unroll
      for (int q = 0; q < 4; ++q) bA[r][q] = *(const vf4*)(gp + (q << 2));
    }
    __builtin_amdgcn_sched_barrier(0);

    // half 1: steps j0+8..j0+15 from bB (bit positions 8..15, force idx (9+s)&15)
    #pragma unroll
    for (int s = 0; s < 8; ++s) DP_STEP(bB[s], j0 + 8 + s, 8 + s, (9 + s) & 15);
    __builtin_amdgcn_sched_barrier(0);

    // issue loads rows j0+24..j0+31 into bB (used next iteration, half 1)
    #pragma unroll
    for (int r = 0; r < 8; ++r) {
      int rr = j0 + 24 + r; if (rr > TYN - 1) rr = TYN - 1;
      const float* gp = vb + ((size_t)rr << 10);
      #pragma unroll
      for (int q = 0; q < 4; ++q) bB[r][q] = *(const vf4*)(gp + (q << 2));
    }
    __builtin_amdgcn_sched_barrier(0);

    const int h = j0 >> 4;
    #pragma unroll
    for (int i = 0; i < 16; ++i) sw16[(i << 8) + h] = (u16)bh[i];
  }
#undef DP_STEP
}

// ---------------- K4: backtrack (run-skipping on transposed bits) ----------------
__global__ __launch_bounds__(256) void k4_backtrack(
    const u32* __restrict__ staysW, const int* __restrict__ xlen, const int* __restrict__ mlen,
    int* __restrict__ idxArr, float* __restrict__ out_logw) {
  int b = blockIdx.x;
  int xl = xlen[b], ml = mlen[b];
  int t = threadIdx.x;
  __shared__ u32 win[64][128];
  __shared__ u16 lidx[TYN];
  __shared__ u16 ldur[TXN];
  __shared__ int st[3];

  for (int i = t; i < TXN; i += 256) ldur[i] = 0;
  if (t == 0) { st[0] = xl - 1; st[1] = ml - 1; st[2] = ml - 1; }
  __syncthreads();

  int wb = (xl - 1) >> 6;
  for (int i = t; i < 64 * 128; i += 256) {
    int r = i >> 7, wq = i & 127;
    win[r][wq] = staysW[((size_t)(b * TXN + (wb << 6) + r) << 7) + wq];
  }
  __syncthreads();

  while (true) {
    if (t == 0) {
      int idx = st[0], j = st[1], end = st[2];
      while (j >= 0 && (idx >> 6) == wb) {
        u32 w = win[idx & 63][j >> 5];
        int p = j & 31;
        u32 below = w << (31 - p);
        u32 inv = ~below;
        int ones = (inv != 0u) ? __builtin_clz(inv) : 32;
        if (ones > p) {
          j -= p + 1;                      // whole rest of word is "stay"
        } else {
          int jz = j - ones;               // dir==0 at step jz -> move down
          for (int q = jz; q <= end; ++q) lidx[q] = (u16)idx;
          ldur[idx] = (u16)(end - jz + 1);
          end = jz - 1;
          j = jz - 1;
          idx -= 1;
        }
      }
      if (j < 0) {
        for (int q = 0; q <= end; ++q) lidx[q] = (u16)idx;
        if (idx >= 0 && end >= 0) ldur[idx] = (u16)(end + 1);
      }
      st[0] = idx; st[1] = j; st[2] = end;
    }
    __syncthreads();
    if (st[1] < 0) break;
    wb = st[0] >> 6;
    for (int i = t; i < 64 * 128; i += 256) {
      int r = i >> 7, wq = i & 127;
      win[r][wq] = staysW[((size_t)(b * TXN + (wb << 6) + r) << 7) + wq];
    }
    __syncthreads();
  }

  for (int q = t; q < TYN; q += 256) idxArr[b * TYN + q] = (q < ml) ? (int)lidx[q] : -1;
  for (int x = t; x < TXN; x += 256)
    out_logw[b * TXN + x] = (x < xl) ? logf(1e-8f + (float)ldur[x]) : 0.f;
}

// ---------------- K5a: write attn (full pass, 0/1) ----------------
__global__ __launch_bounds__(256) void k5_attn(
    const int* __restrict__ idxArr, float* __restrict__ attn) {
  int b = blockIdx.z;
  int x = blockIdx.y;
  int j = blockIdx.x * 1024 + threadIdx.x * 4;
  int4 iv = *(const int4*)(idxArr + b * TYN + j);
  float4 o;
  o.x = (iv.x == x) ? 1.f : 0.f;
  o.y = (iv.y == x) ? 1.f : 0.f;
  o.z = (iv.z == x) ? 1.f : 0.f;
  o.w = (iv.w == x) ? 1.f : 0.f;
  *(float4*)(attn + ((size_t)(b * TXN + x)) * TYN + j) = o;
}

// ---------------- K5b: z_m gather ----------------
__global__ __launch_bounds__(256) void k5_zm(
    const int* __restrict__ idxArr, const float* __restrict__ xres, float* __restrict__ zm) {
  int bid = blockIdx.x; int b = bid >> 8; int c = bid & 255;
  const float* row = xres + (size_t)(b * DRES + c) * TXN;
  float* orow = zm + (size_t)(b * DRES + c) * TYN;
  const int* ia = idxArr + b * TYN;
  for (int j = threadIdx.x; j < TYN; j += 256) {
    int idx = ia[j];
    orow[j] = (idx >= 0) ? row[idx] : 0.f;
  }
}

// ---------------- K5c: mel_proj gather + loss partials ----------------
__global__ __launch_bounds__(256) void k5_mproj(
    const int* __restrict__ idxArr, const float* __restrict__ xm,
    const float* __restrict__ noise, const float* __restrict__ mel,
    float* __restrict__ mproj, float* __restrict__ partials) {
  int bid = blockIdx.x; int b = bid / CMEL; int c = bid % CMEL;
  const float* row  = xm    + (size_t)(b * CMEL + c) * TXN;
  const float* nrow = noise + (size_t)(b * CMEL + c) * TYN;
  const float* mrow = mel   + (size_t)(b * CMEL + c) * TYN;
  float* orow = mproj + (size_t)(b * CMEL + c) * TYN;
  const int* ia = idxArr + b * TYN;
  float acc = 0.f;
  for (int j = threadIdx.x; j < TYN; j += 256) {
    int idx = ia[j];
    float g = (idx >= 0) ? row[idx] : 0.f;
    float mp = g + nrow[j];
    orow[j] = mp;
    float d = mp - mrow[j];
    acc += (idx >= 0) ? fabsf(d) : 0.f;
  }
  #pragma unroll
  for (int o = 32; o; o >>= 1) acc += __shfl_down(acc, o);
  __shared__ float ws4[4];
  if ((threadIdx.x & 63) == 0) ws4[threadIdx.x >> 6] = acc;
  __syncthreads();
  if (threadIdx.x == 0) partials[bid] = (ws4[0] + ws4[1]) + (ws4[2] + ws4[3]);
}

// ---------------- K6: final loss reduce ----------------
__global__ __launch_bounds__(256) void k6_loss(
    const float* __restrict__ partials, float* __restrict__ out_loss) {
  float acc = 0.f;
  for (int i = threadIdx.x; i < BB * CMEL; i += 256) acc += partials[i];
  #pragma unroll
  for (int o = 32; o; o >>= 1) acc += __shfl_down(acc, o);
  __shared__ float ws4[4];
  if ((threadIdx.x & 63) == 0) ws4[threadIdx.x >> 6] = acc;
  __syncthreads();
  if (threadIdx.x == 0)
    out_loss[0] = ((ws4[0] + ws4[1]) + (ws4[2] + ws4[3])) * (1.0f / ((float)BB * CMEL * TYN));
}

extern "C" void kernel_launch(void* const* d_in, const int* in_sizes, int n_in,
                              void* d_out, int out_size, void* d_ws, size_t ws_size,
                              hipStream_t stream) {
  const float* xm    = (const float*)d_in[0];
  const float* xres  = (const float*)d_in[1];
  const float* mel   = (const float*)d_in[2];
  const int*   xlen  = (const int*)d_in[3];
  const int*   mlen  = (const int*)d_in[4];
  const float* noise = (const float*)d_in[5];

  float* out = (float*)d_out;
  float* out_zm    = out + OFF_ZM;
  float* out_zmask = out + OFF_ZMASK;
  float* out_attn  = out + OFF_ATTN;
  float* out_logw  = out + OFF_LOGW;
  float* out_loss  = out + OFF_LOSS;
  float* out_mproj = out + OFF_MPROJ;

  char* ws = (char*)d_ws;
  float* x2n      = (float*)(ws + WS_X2);
  float* z2n      = (float*)(ws + WS_Z2);
  int*   idxArr   = (int*)(ws + WS_IDX);
  float* partials = (float*)(ws + WS_PART);

  // scratch aliases inside output regions (consumed before region is rewritten)
  float* valT   = out_attn;        // [b][j][x], read by K3, overwritten by K5a
  u32*   staysW = (u32*)out_zm;    // 8 MB of z_m region, read by K4, overwritten by K5b

  hipLaunchKernelGGL(k1_prep, dim3(BB, 5), dim3(1024), 0, stream, xm, mel, mlen, x2n, z2n, out_zmask);
  hipLaunchKernelGGL(k2_corr, dim3(8, 32, BB), dim3(256), 0, stream, xm, mel, x2n, z2n, xlen, mlen, valT);
  hipLaunchKernelGGL(k3_dp, dim3(BB), dim3(64), 0, stream, valT, mlen, staysW);
  hipLaunchKernelGGL(k4_backtrack, dim3(BB), dim3(256), 0, stream, staysW, xlen, mlen, idxArr, out_logw);
  hipLaunchKernelGGL(k5_attn, dim3(4, TXN, BB), dim3(256), 0, stream, idxArr, out_attn);
  hipLaunchKernelGGL(k5_zm, dim3(BB * DRES), dim3(256), 0, stream, idxArr, xres, out_zm);
  hipLaunchKernelGGL(k5_mproj, dim3(BB * CMEL), dim3(256), 0, stream, idxArr, xm, noise, mel, out_mproj, partials);
  hipLaunchKernelGGL(k6_loss, dim3(1), dim3(256), 0, stream, partials, out_loss);
}